// Round 5
// baseline (3219.038 us; speedup 1.0000x reference)
//
#include <hip/hip_runtime.h>
#include <math.h>

#define B_   128
#define L_   401
#define DM   192
#define DI   384
#define DSTATE 16
#define DTR  12
#define SEG  8
#define SEGLEN 51    // ceil(401/8); segments 0..6 full 51, segment 7 = 44

typedef __attribute__((ext_vector_type(8))) short s8b;     // 8 bf16
typedef __attribute__((ext_vector_type(4))) float f4;
typedef __attribute__((ext_vector_type(16))) float f16v;

__device__ __forceinline__ unsigned short f2bf(float x) {
    unsigned int u = __builtin_bit_cast(unsigned int, x);
    unsigned int r = (u + 0x7fffu + ((u >> 16) & 1u)) >> 16;
    return (unsigned short)r;
}
__device__ __forceinline__ float bf2f(unsigned short x) {
    unsigned int u = ((unsigned int)x) << 16;
    return __builtin_bit_cast(float, u);
}

// ---------------- weight fp32 -> bf16 ----------------
__global__ __launch_bounds__(256) void convw_kernel(
    const float* __restrict__ src, unsigned short* __restrict__ dst, int total)
{
    for (int idx = blockIdx.x * 256 + threadIdx.x; idx < total; idx += gridDim.x * 256)
        dst[idx] = f2bf(src[idx]);
}

// ---------------- build fused x_proj+dt_proj weight: [4][416][384] bf16 --------
__global__ __launch_bounds__(256) void build_xdtw_kernel(
    const float* __restrict__ xp_w, const float* __restrict__ dt_w,
    unsigned short* __restrict__ out)
{
    int idx = blockIdx.x * 256 + threadIdx.x;
    if (idx >= 4 * 416 * 384) return;
    int k  = idx % 384;
    int rr = (idx / 384) % 416;
    int i  = idx / (384 * 416);
    const float* xp = xp_w + (size_t)i * 44 * 384;
    float v;
    if (rr < 384) {
        const float* dw = dt_w + (size_t)i * 384 * 12 + rr * 12;
        v = 0.f;
        #pragma unroll
        for (int r = 0; r < 12; ++r) v = fmaf(dw[r], xp[r * 384 + k], v);
    } else {
        v = xp[(12 + (rr - 384)) * 384 + k];
    }
    out[idx] = f2bf(v);
}

// ---------------- embed ----------------
__global__ void embed_kernel(const float* __restrict__ imgs,
                             const float* __restrict__ pe_w,
                             const float* __restrict__ pe_b,
                             const float* __restrict__ cls_token,
                             const float* __restrict__ pos_embed,
                             float* __restrict__ x)
{
    int row = blockIdx.x;
    int l = row % L_;
    int b = row / L_;
    int d = threadIdx.x;
    float v;
    if (l < 400) {
        const float* f = imgs + (size_t)b * 1600 + (size_t)l * 4;
        const float* pw = pe_w + d * 4;
        v = pe_b[d];
        v = fmaf(f[0], pw[0], v);
        v = fmaf(f[1], pw[1], v);
        v = fmaf(f[2], pw[2], v);
        v = fmaf(f[3], pw[3], v);
        v += pos_embed[l * DM + d];
    } else {
        v = cls_token[d] + pos_embed[400 * DM + d];
    }
    x[(size_t)row * DM + d] = v;
}

// ---------------- rms norm (+residual), bf16 normed output ----------------
__global__ __launch_bounds__(256) void rms_kernel(
    const float* hidden, float* residual, unsigned short* __restrict__ nbf,
    const float* __restrict__ w, int add, int nrows)
{
    int wv   = threadIdx.x >> 6;
    int lane = threadIdx.x & 63;
    int row  = blockIdx.x * 4 + wv;
    if (row >= nrows) return;
    const float* hr = hidden + (size_t)row * DM;
    float* rr = residual + (size_t)row * DM;
    float x0 = hr[lane], x1 = hr[lane + 64], x2 = hr[lane + 128];
    if (add) { x0 += rr[lane]; x1 += rr[lane + 64]; x2 += rr[lane + 128]; }
    rr[lane] = x0; rr[lane + 64] = x1; rr[lane + 128] = x2;
    float ss = x0 * x0 + x1 * x1 + x2 * x2;
    #pragma unroll
    for (int off = 32; off > 0; off >>= 1) ss += __shfl_down(ss, off);
    ss = __shfl(ss, 0);
    float scale = rsqrtf(ss / (float)DM + 1e-5f);
    unsigned short* nr = nbf + (size_t)row * DM;
    nr[lane]       = f2bf(x0 * scale * w[lane]);
    nr[lane + 64]  = f2bf(x1 * scale * w[lane + 64]);
    nr[lane + 128] = f2bf(x2 * scale * w[lane + 128]);
}

// ---------------- bf16 MFMA GEMM, compile-time K, 4x4 register blocking -----------
// Block 256 thr = 4 waves; wave computes 64 rows x 64 cols (16 MFMAs / K-step).
// Grid: (ceil(N/64), ceil(M/256)). If splitN>0: cols >= splitN go raw fp32 to C2.
template<int K>
__global__ __launch_bounds__(256, 2) void gemm_bf_t(
    const unsigned short* __restrict__ A, int lda,
    const unsigned short* __restrict__ W, int ldw,
    float* __restrict__ C, int ldc,
    unsigned short* __restrict__ Cbf, int ldcbf,
    float* __restrict__ C2, int ldc2, int splitN,
    const float* __restrict__ bias,
    int M, int N, int act)
{
    int w    = threadIdx.x >> 6;
    int lane = threadIdx.x & 63;
    int q    = lane >> 4;
    int r    = lane & 15;
    int bm   = blockIdx.y * 256 + w * 64;
    int bn   = blockIdx.x * 64;

    const unsigned short* Ap[4];
    const unsigned short* Wp[4];
    #pragma unroll
    for (int f = 0; f < 4; ++f) {
        int arow = bm + f * 16 + r; if (arow > M - 1) arow = M - 1;
        Ap[f] = A + (size_t)arow * lda + q * 8;
        int n = bn + f * 16 + r;    if (n > N - 1) n = N - 1;
        Wp[f] = W + (size_t)n * ldw + q * 8;
    }

    f4 acc[4][4];
    #pragma unroll
    for (int f = 0; f < 4; ++f)
        #pragma unroll
        for (int c = 0; c < 4; ++c) acc[f][c] = {0.f, 0.f, 0.f, 0.f};

    #pragma unroll
    for (int k0 = 0; k0 < K; k0 += 32) {
        s8b af[4], bf[4];
        #pragma unroll
        for (int f = 0; f < 4; ++f) {
            af[f] = *(const s8b*)(Ap[f] + k0);
            bf[f] = *(const s8b*)(Wp[f] + k0);
        }
        #pragma unroll
        for (int f = 0; f < 4; ++f)
            #pragma unroll
            for (int c = 0; c < 4; ++c)
                acc[f][c] = __builtin_amdgcn_mfma_f32_16x16x32_bf16(af[f], bf[c], acc[f][c], 0, 0, 0);
    }

    // C/D layout: col = lane&15, row = (lane>>4)*4 + reg
    #pragma unroll
    for (int f = 0; f < 4; ++f) {
        #pragma unroll
        for (int c = 0; c < 4; ++c) {
            int gn = bn + c * 16 + r;
            if (gn >= N) continue;
            #pragma unroll
            for (int reg = 0; reg < 4; ++reg) {
                int gm = bm + f * 16 + q * 4 + reg;
                if (gm >= M) continue;
                float v = acc[f][c][reg];
                if (splitN > 0 && gn >= splitN) {
                    C2[(size_t)gm * ldc2 + (gn - splitN)] = v;
                } else {
                    if (bias) v += bias[gn];
                    if (act == 1) v = fmaxf(v, 0.f) + log1pf(expf(-fabsf(v)));
                    if (C)   C[(size_t)gm * ldc + gn] = v;
                    if (Cbf) Cbf[(size_t)gm * ldcbf + gn] = f2bf(v);
                }
            }
        }
    }
}

// ---------------- causal depthwise conv (width 4) + silu, 4 channels/thread -------
__global__ __launch_bounds__(256) void conv_silu_kernel(
    const unsigned short* __restrict__ xzbf, const float* __restrict__ cw,
    const float* __restrict__ cb, unsigned short* __restrict__ xcbf, int total4)
{
    int idx = blockIdx.x * 256 + threadIdx.x;
    if (idx >= total4) return;
    int d4 = (idx % (DI / 4)) * 4;
    int bl = idx / (DI / 4);
    int l  = bl % L_;
    float acc[4];
    #pragma unroll
    for (int c = 0; c < 4; ++c) acc[c] = cb[d4 + c];
    #pragma unroll
    for (int k = 0; k < 4; ++k) {
        int ls = l + k - 3;
        if (ls >= 0) {
            ushort4 xv = *(const ushort4*)(xzbf + (size_t)(bl - l + ls) * (2 * DI) + d4);
            acc[0] = fmaf(cw[(d4 + 0) * 4 + k], bf2f(xv.x), acc[0]);
            acc[1] = fmaf(cw[(d4 + 1) * 4 + k], bf2f(xv.y), acc[1]);
            acc[2] = fmaf(cw[(d4 + 2) * 4 + k], bf2f(xv.z), acc[2]);
            acc[3] = fmaf(cw[(d4 + 3) * 4 + k], bf2f(xv.w), acc[3]);
        }
    }
    ushort4 out;
    out.x = f2bf(acc[0] / (1.f + __expf(-acc[0])));
    out.y = f2bf(acc[1] / (1.f + __expf(-acc[1])));
    out.z = f2bf(acc[2] / (1.f + __expf(-acc[2])));
    out.w = f2bf(acc[3] / (1.f + __expf(-acc[3])));
    *(ushort4*)(xcbf + (size_t)bl * DI + d4) = out;
}

// ---------------- scan pass 1: per-segment transition (P, h_local) ----------------
__global__ __launch_bounds__(64) void scan1_kernel(
    const unsigned short* __restrict__ dt,
    const unsigned short* __restrict__ xcbf,
    const float* __restrict__ dbl,
    const float* __restrict__ A_log,
    float* __restrict__ Hbuf)
{
    int j = blockIdx.x % 7;
    int t = blockIdx.x / 7;
    int b = t / 6;
    int d = (t % 6) * 64 + threadIdx.x;
    f16v Av, hv, Pv;
    #pragma unroll
    for (int s = 0; s < 16; ++s) { Av[s] = -expf(A_log[d * 16 + s]); hv[s] = 0.f; Pv[s] = 1.f; }

    size_t base = (size_t)b * L_;
    const unsigned short* dtp = dt + base * DI + d;
    const unsigned short* xcp = xcbf + base * DI + d;
    const float* bp = dbl + base * 32;
    int l0 = j * SEGLEN;
    int lend = l0 + SEGLEN;

    float dtv[4], xcv[4];
    #pragma unroll
    for (int i = 0; i < 4; ++i) {
        dtv[i] = bf2f(dtp[(size_t)(l0 + i) * DI]);
        xcv[i] = bf2f(xcp[(size_t)(l0 + i) * DI]);
    }
    f16v B0, B1;
    #pragma unroll
    for (int s2 = 0; s2 < 16; ++s2) { B0[s2] = bp[(size_t)l0 * 32 + s2]; B1[s2] = bp[(size_t)(l0 + 1) * 32 + s2]; }

#define S1_BODY(dt_, xc_, Bv)                                            \
    { float coef = (dt_) * (xc_);                                        \
      _Pragma("unroll")                                                  \
      for (int s = 0; s < 16; ++s) {                                     \
          float dA = __expf((dt_) * Av[s]);                              \
          hv[s] = fmaf(hv[s], dA, coef * Bv[s]);                         \
          Pv[s] *= dA; } }
#define S1_PF_B(Bv, lq)                                                  \
    if ((lq) < lend) { _Pragma("unroll")                                 \
      for (int s2 = 0; s2 < 16; ++s2) Bv[s2] = bp[(size_t)(lq) * 32 + s2]; }
#define S1_PF_S(i_, lq)                                                  \
    if ((lq) < lend) { dtv[i_] = bf2f(dtp[(size_t)(lq) * DI]);           \
      xcv[i_] = bf2f(xcp[(size_t)(lq) * DI]); }

    for (int l = l0; l < lend; l += 4) {
        S1_BODY(dtv[0], xcv[0], B0); S1_PF_B(B0, l + 2); S1_PF_S(0, l + 4);
        if (l + 1 < lend) { S1_BODY(dtv[1], xcv[1], B1); S1_PF_B(B1, l + 3); S1_PF_S(1, l + 5); }
        if (l + 2 < lend) { S1_BODY(dtv[2], xcv[2], B0); S1_PF_B(B0, l + 4); S1_PF_S(2, l + 6); }
        if (l + 3 < lend) { S1_BODY(dtv[3], xcv[3], B1); S1_PF_B(B1, l + 5); S1_PF_S(3, l + 7); }
    }
    float* Hp = Hbuf + (size_t)blockIdx.x * 2048 + threadIdx.x;
    #pragma unroll
    for (int s = 0; s < 16; ++s) { Hp[s * 64] = Pv[s]; Hp[(16 + s) * 64] = hv[s]; }
}

// ---------------- scan pass 2: compose h_start, scan segment, emit y ----------------
__global__ __launch_bounds__(64) void scan2_kernel(
    const unsigned short* __restrict__ dt,
    const unsigned short* __restrict__ xcbf,
    const unsigned short* __restrict__ xzbf,
    const float* __restrict__ dbl,
    const float* __restrict__ A_log,
    const float* __restrict__ Dp,
    const float* __restrict__ Hbuf,
    unsigned short* __restrict__ ybf)
{
    int j = blockIdx.x & 7;
    int t = blockIdx.x >> 3;
    int b = t / 6;
    int d = (t % 6) * 64 + threadIdx.x;
    f16v Av, hv;
    #pragma unroll
    for (int s = 0; s < 16; ++s) { Av[s] = -expf(A_log[d * 16 + s]); hv[s] = 0.f; }
    float Dval = Dp[d];

    const float* Hp = Hbuf + (size_t)t * 7 * 2048 + threadIdx.x;
    for (int k = 0; k < j; ++k) {
        const float* hp = Hp + (size_t)k * 2048;
        #pragma unroll
        for (int s = 0; s < 16; ++s)
            hv[s] = fmaf(hp[s * 64], hv[s], hp[(16 + s) * 64]);
    }

    size_t base = (size_t)b * L_;
    const unsigned short* dtp = dt + base * DI + d;
    const unsigned short* xcp = xcbf + base * DI + d;
    const unsigned short* zp  = xzbf + base * (2 * DI) + DI + d;
    const float* bcp = dbl + base * 32;
    unsigned short* yp = ybf + base * DI + d;
    int l0 = j * SEGLEN;
    int lend = l0 + SEGLEN; if (lend > L_) lend = L_;

    float dtv[4], xcv[4], zv[4];
    #pragma unroll
    for (int i = 0; i < 4; ++i) {
        dtv[i] = bf2f(dtp[(size_t)(l0 + i) * DI]);
        xcv[i] = bf2f(xcp[(size_t)(l0 + i) * DI]);
        zv[i]  = bf2f(zp[(size_t)(l0 + i) * (2 * DI)]);
    }
    f16v B0, C0, B1, C1;
    #pragma unroll
    for (int s2 = 0; s2 < 16; ++s2) {
        B0[s2] = bcp[(size_t)l0 * 32 + s2];       C0[s2] = bcp[(size_t)l0 * 32 + 16 + s2];
        B1[s2] = bcp[(size_t)(l0 + 1) * 32 + s2]; C1[s2] = bcp[(size_t)(l0 + 1) * 32 + 16 + s2];
    }

#define S2_BODY(dt_, xc_, z_, Bv, Cv, lcur)                              \
    { float coef = (dt_) * (xc_); float y = 0.f;                         \
      _Pragma("unroll")                                                  \
      for (int s = 0; s < 16; ++s) {                                     \
          float dA = __expf((dt_) * Av[s]);                              \
          hv[s] = fmaf(hv[s], dA, coef * Bv[s]);                         \
          y = fmaf(hv[s], Cv[s], y); }                                   \
      float yv = fmaf(Dval, (xc_), y);                                   \
      float sg = 1.f / (1.f + __expf(-(z_)));                            \
      yp[(size_t)(lcur) * DI] = f2bf(yv * ((z_) * sg)); }
#define S2_PF_BC(Bv, Cv, lq)                                             \
    if ((lq) < lend) { _Pragma("unroll")                                 \
      for (int s2 = 0; s2 < 16; ++s2) {                                  \
          Bv[s2] = bcp[(size_t)(lq) * 32 + s2];                          \
          Cv[s2] = bcp[(size_t)(lq) * 32 + 16 + s2]; } }
#define S2_PF_S(i_, lq)                                                  \
    if ((lq) < lend) { dtv[i_] = bf2f(dtp[(size_t)(lq) * DI]);           \
      xcv[i_] = bf2f(xcp[(size_t)(lq) * DI]);                            \
      zv[i_]  = bf2f(zp[(size_t)(lq) * (2 * DI)]); }

    for (int l = l0; l < lend; l += 4) {
        S2_BODY(dtv[0], xcv[0], zv[0], B0, C0, l); S2_PF_BC(B0, C0, l + 2); S2_PF_S(0, l + 4);
        if (l + 1 < lend) { S2_BODY(dtv[1], xcv[1], zv[1], B1, C1, l + 1); S2_PF_BC(B1, C1, l + 3); S2_PF_S(1, l + 5); }
        if (l + 2 < lend) { S2_BODY(dtv[2], xcv[2], zv[2], B0, C0, l + 2); S2_PF_BC(B0, C0, l + 4); S2_PF_S(2, l + 6); }
        if (l + 3 < lend) { S2_BODY(dtv[3], xcv[3], zv[3], B1, C1, l + 3); S2_PF_BC(B1, C1, l + 5); S2_PF_S(3, l + 7); }
    }
}

// ---------------- final rms on cls row only ----------------
__global__ __launch_bounds__(64) void final_kernel(
    const float* __restrict__ hidden, const float* __restrict__ residual,
    const float* __restrict__ wf, float* __restrict__ v_sem)
{
    int b = blockIdx.x;
    int lane = threadIdx.x;
    size_t row = (size_t)b * L_ + 400;
    const float* hr = hidden + row * DM;
    const float* rr = residual + row * DM;
    float x0 = hr[lane] + rr[lane];
    float x1 = hr[lane + 64] + rr[lane + 64];
    float x2 = hr[lane + 128] + rr[lane + 128];
    float ss = x0 * x0 + x1 * x1 + x2 * x2;
    #pragma unroll
    for (int off = 32; off > 0; off >>= 1) ss += __shfl_down(ss, off);
    ss = __shfl(ss, 0);
    float scale = rsqrtf(ss / (float)DM + 1e-5f);
    v_sem[b * DM + lane]       = x0 * scale * wf[lane];
    v_sem[b * DM + lane + 64]  = x1 * scale * wf[lane + 64];
    v_sem[b * DM + lane + 128] = x2 * scale * wf[lane + 128];
}

// ---------------- tiny MLPs + head ----------------
__global__ __launch_bounds__(256) void mlp1_kernel(
    const float* __restrict__ pl, const float* __restrict__ iat,
    const float* __restrict__ w, const float* __restrict__ bias,
    float* __restrict__ out)
{
    int idx = blockIdx.x * 256 + threadIdx.x;
    if (idx >= 128 * 128) return;
    int b = idx / 128, j = idx % 128;
    float acc = bias[j];
    const float* wr = w + j * 200;
    const float* pr = pl + b * 100;
    const float* ir = iat + b * 100;
    for (int k = 0; k < 100; ++k) acc = fmaf(pr[k], wr[k], acc);
    for (int k = 0; k < 100; ++k) acc = fmaf(ir[k], wr[100 + k], acc);
    out[idx] = fmaxf(acc, 0.f);
}

__global__ __launch_bounds__(256) void mlp2_kernel(
    const float* __restrict__ h1, const float* __restrict__ w,
    const float* __restrict__ bias, float* __restrict__ out)
{
    int idx = blockIdx.x * 256 + threadIdx.x;
    if (idx >= 128 * 128) return;
    int b = idx / 128, j = idx % 128;
    float acc = bias[j];
    const float* wr = w + j * 128;
    const float* hr = h1 + b * 128;
    for (int k = 0; k < 128; ++k) acc = fmaf(hr[k], wr[k], acc);
    out[idx] = acc;
}

__global__ __launch_bounds__(256) void head_kernel(
    const float* __restrict__ v_sem, const float* __restrict__ v_stat,
    const float* __restrict__ w, const float* __restrict__ bias,
    float* __restrict__ out)
{
    int idx = blockIdx.x * 256 + threadIdx.x;
    if (idx >= 128 * 20) return;
    int b = idx / 20, o = idx % 20;
    float acc = bias[o];
    const float* wr = w + o * 320;
    const float* vs = v_sem + b * DM;
    const float* vt = v_stat + b * 128;
    for (int k = 0; k < DM; ++k)  acc = fmaf(vs[k], wr[k], acc);
    for (int k = 0; k < 128; ++k) acc = fmaf(vt[k], wr[DM + k], acc);
    out[idx] = acc;
}

extern "C" void kernel_launch(void* const* d_in, const int* in_sizes, int n_in,
                              void* d_out, int out_size, void* d_ws, size_t ws_size,
                              hipStream_t stream)
{
    const float* imgs       = (const float*)d_in[0];
    const float* pl         = (const float*)d_in[1];
    const float* iat        = (const float*)d_in[2];
    const float* pe_w       = (const float*)d_in[3];
    const float* pe_b       = (const float*)d_in[4];
    const float* cls_token  = (const float*)d_in[5];
    const float* pos_embed  = (const float*)d_in[6];
    const float* norm_ws    = (const float*)d_in[7];
    const float* in_proj_ws = (const float*)d_in[8];
    const float* conv_ws    = (const float*)d_in[9];
    const float* conv_bs    = (const float*)d_in[10];
    const float* x_proj_ws  = (const float*)d_in[11];
    const float* dt_proj_ws = (const float*)d_in[12];
    const float* dt_proj_bs = (const float*)d_in[13];
    const float* A_logs     = (const float*)d_in[14];
    const float* Ds         = (const float*)d_in[15];
    const float* out_proj_ws= (const float*)d_in[16];
    const float* norm_f_w   = (const float*)d_in[17];
    const float* mlp1_w     = (const float*)d_in[18];
    const float* mlp1_b     = (const float*)d_in[19];
    const float* mlp2_w     = (const float*)d_in[20];
    const float* mlp2_b     = (const float*)d_in[21];
    const float* head_w     = (const float*)d_in[22];
    const float* head_b     = (const float*)d_in[23];

    float* ws = (float*)d_ws;
    size_t off = 0;
    float* v_sem  = ws + off; off += 128 * DM;
    float* h1     = ws + off; off += 128 * 128;
    float* v_stat = ws + off; off += 128 * 128;
    unsigned short* inw_bf = (unsigned short*)(ws + off); off += (size_t)4 * 768 * DM / 2;
    unsigned short* ow_bf  = (unsigned short*)(ws + off); off += (size_t)4 * DM * DI / 2;
    unsigned short* xdtw   = (unsigned short*)(ws + off); off += (size_t)4 * 416 * DI / 2;
    float* chunkbuf = ws + off;
    size_t small_floats = off;

    // per-b floats: rows(401)*[hidden 192 + residual 192 + dtbf 192 + dbl 32 +
    //   nbf 96 + xzbf 384 + xcbf 192 + ybf 192] + Hbuf 6*7*2048
    const size_t per_b = (size_t)L_ * (192 + 192 + 192 + 32 + 96 + 384 + 192 + 192)
                       + (size_t)6 * 7 * 2048;
    size_t avail = ws_size / sizeof(float);
    avail = (avail > small_floats) ? (avail - small_floats) : 0;
    int Bc = (int)(avail / per_b);
    if (Bc > B_) Bc = B_;
    if (Bc < 1) Bc = 1;

    // weight prep (once per call; ws re-poisoned before every timed call)
    convw_kernel<<<512, 256, 0, stream>>>(in_proj_ws, inw_bf, 4 * 768 * DM);
    convw_kernel<<<512, 256, 0, stream>>>(out_proj_ws, ow_bf, 4 * DM * DI);
    build_xdtw_kernel<<<(4 * 416 * 384 + 255) / 256, 256, 0, stream>>>(x_proj_ws, dt_proj_ws, xdtw);

    for (int b0 = 0; b0 < B_; b0 += Bc) {
        int bc = (B_ - b0 < Bc) ? (B_ - b0) : Bc;
        int rows = bc * L_;
        float* hidden   = chunkbuf;
        float* residual = hidden + (size_t)rows * DM;
        float* dbl      = residual + (size_t)rows * DM;            // fp32 B,C [rows][32]
        float* Hbuf     = dbl + (size_t)rows * 32;                 // bc*6*7*2048
        unsigned short* dtbf = (unsigned short*)(Hbuf + (size_t)bc * 6 * 7 * 2048);
        unsigned short* nbf  = dtbf + (size_t)rows * DI;           // [rows][192]
        unsigned short* xzbf = nbf + (size_t)rows * DM;            // [rows][768]
        unsigned short* xcbf = xzbf + (size_t)rows * 2 * DI;       // [rows][384]
        unsigned short* ybf  = xcbf + (size_t)rows * DI;           // [rows][384]

        int gmy = (rows + 255) / 256;

        embed_kernel<<<rows, DM, 0, stream>>>(imgs + (size_t)b0 * 1600,
                                              pe_w, pe_b, cls_token, pos_embed, hidden);

        for (int i = 0; i < 4; ++i) {
            rms_kernel<<<(rows + 3) / 4, 256, 0, stream>>>(
                hidden, residual, nbf, norm_ws + i * DM, i > 0 ? 1 : 0, rows);
            // in_proj -> xzbf (bf16): (rows,192)x(768,192)^T
            gemm_bf_t<192><<<dim3(12, gmy), 256, 0, stream>>>(
                nbf, DM, inw_bf + (size_t)i * 768 * DM, DM,
                nullptr, 0, xzbf, 2 * DI, nullptr, 0, 0,
                nullptr, rows, 2 * DI, 0);
            // conv + silu -> xcbf
            int total4 = rows * (DI / 4);
            conv_silu_kernel<<<(total4 + 255) / 256, 256, 0, stream>>>(
                xzbf, conv_ws + i * DI * 4, conv_bs + i * DI, xcbf, total4);
            // fused x_proj+dt_proj: (rows,384)x(416,384)^T; cols<384 -> softplus dt bf16,
            // cols>=384 -> B,C raw fp32 (ld 32)
            gemm_bf_t<384><<<dim3(7, gmy), 256, 0, stream>>>(
                xcbf, DI, xdtw + (size_t)i * 416 * DI, DI,
                nullptr, 0, dtbf, DI, dbl, 32, DI,
                dt_proj_bs + i * DI, rows, 416, 1);
            // segmented scan
            scan1_kernel<<<bc * 6 * 7, 64, 0, stream>>>(
                dtbf, xcbf, dbl, A_logs + (size_t)i * DI * DSTATE, Hbuf);
            scan2_kernel<<<bc * 6 * 8, 64, 0, stream>>>(
                dtbf, xcbf, xzbf, dbl, A_logs + (size_t)i * DI * DSTATE,
                Ds + i * DI, Hbuf, ybf);
            // out_proj: (rows,384)x(192,384)^T -> hidden fp32
            gemm_bf_t<384><<<dim3(3, gmy), 256, 0, stream>>>(
                ybf, DI, ow_bf + (size_t)i * DM * DI, DI,
                hidden, DM, nullptr, 0, nullptr, 0, 0,
                nullptr, rows, DM, 0);
        }

        final_kernel<<<bc, 64, 0, stream>>>(hidden, residual, norm_f_w,
                                            v_sem + (size_t)b0 * DM);
    }

    mlp1_kernel<<<64, 256, 0, stream>>>(pl, iat, mlp1_w, mlp1_b, h1);
    mlp2_kernel<<<64, 256, 0, stream>>>(h1, mlp2_w, mlp2_b, v_stat);
    head_kernel<<<10, 256, 0, stream>>>(v_sem, v_stat, head_w, head_b, (float*)d_out);
}

// Round 6
// 2841.538 us; speedup vs baseline: 1.1329x; 1.1329x over previous
//
#include <hip/hip_runtime.h>
#include <math.h>

#define B_   128
#define L_   401
#define DM   192
#define DI   384
#define DSTATE 16
#define DTR  12
#define SEG  8
#define SEGLEN 51    // ceil(401/8); segments 0..6 full 51, segment 7 = 44

typedef __attribute__((ext_vector_type(8))) short s8b;     // 8 bf16
typedef __attribute__((ext_vector_type(4))) float f4;
typedef __attribute__((ext_vector_type(16))) float f16v;

__device__ __forceinline__ unsigned short f2bf(float x) {
    unsigned int u = __builtin_bit_cast(unsigned int, x);
    unsigned int r = (u + 0x7fffu + ((u >> 16) & 1u)) >> 16;
    return (unsigned short)r;
}
__device__ __forceinline__ float bf2f(unsigned short x) {
    unsigned int u = ((unsigned int)x) << 16;
    return __builtin_bit_cast(float, u);
}

// ---------------- weight fp32 -> bf16 ----------------
__global__ __launch_bounds__(256) void convw_kernel(
    const float* __restrict__ src, unsigned short* __restrict__ dst, int total)
{
    for (int idx = blockIdx.x * 256 + threadIdx.x; idx < total; idx += gridDim.x * 256)
        dst[idx] = f2bf(src[idx]);
}

// ---------------- build fused x_proj+dt_proj weight: [4][416][384] bf16 --------
__global__ __launch_bounds__(256) void build_xdtw_kernel(
    const float* __restrict__ xp_w, const float* __restrict__ dt_w,
    unsigned short* __restrict__ out)
{
    int idx = blockIdx.x * 256 + threadIdx.x;
    if (idx >= 4 * 416 * 384) return;
    int k  = idx % 384;
    int rr = (idx / 384) % 416;
    int i  = idx / (384 * 416);
    const float* xp = xp_w + (size_t)i * 44 * 384;
    float v;
    if (rr < 384) {
        const float* dw = dt_w + (size_t)i * 384 * 12 + rr * 12;
        v = 0.f;
        #pragma unroll
        for (int r = 0; r < 12; ++r) v = fmaf(dw[r], xp[r * 384 + k], v);
    } else {
        v = xp[(12 + (rr - 384)) * 384 + k];
    }
    out[idx] = f2bf(v);
}

// ---------------- embed ----------------
__global__ void embed_kernel(const float* __restrict__ imgs,
                             const float* __restrict__ pe_w,
                             const float* __restrict__ pe_b,
                             const float* __restrict__ cls_token,
                             const float* __restrict__ pos_embed,
                             float* __restrict__ x)
{
    int row = blockIdx.x;
    int l = row % L_;
    int b = row / L_;
    int d = threadIdx.x;
    float v;
    if (l < 400) {
        const float* f = imgs + (size_t)b * 1600 + (size_t)l * 4;
        const float* pw = pe_w + d * 4;
        v = pe_b[d];
        v = fmaf(f[0], pw[0], v);
        v = fmaf(f[1], pw[1], v);
        v = fmaf(f[2], pw[2], v);
        v = fmaf(f[3], pw[3], v);
        v += pos_embed[l * DM + d];
    } else {
        v = cls_token[d] + pos_embed[400 * DM + d];
    }
    x[(size_t)row * DM + d] = v;
}

// ---------------- rms norm (+residual), bf16 normed output ----------------
__global__ __launch_bounds__(256) void rms_kernel(
    const float* hidden, float* residual, unsigned short* __restrict__ nbf,
    const float* __restrict__ w, int add, int nrows)
{
    int wv   = threadIdx.x >> 6;
    int lane = threadIdx.x & 63;
    int row  = blockIdx.x * 4 + wv;
    if (row >= nrows) return;
    const float* hr = hidden + (size_t)row * DM;
    float* rr = residual + (size_t)row * DM;
    float x0 = hr[lane], x1 = hr[lane + 64], x2 = hr[lane + 128];
    if (add) { x0 += rr[lane]; x1 += rr[lane + 64]; x2 += rr[lane + 128]; }
    rr[lane] = x0; rr[lane + 64] = x1; rr[lane + 128] = x2;
    float ss = x0 * x0 + x1 * x1 + x2 * x2;
    #pragma unroll
    for (int off = 32; off > 0; off >>= 1) ss += __shfl_down(ss, off);
    ss = __shfl(ss, 0);
    float scale = rsqrtf(ss / (float)DM + 1e-5f);
    unsigned short* nr = nbf + (size_t)row * DM;
    nr[lane]       = f2bf(x0 * scale * w[lane]);
    nr[lane + 64]  = f2bf(x1 * scale * w[lane + 64]);
    nr[lane + 128] = f2bf(x2 * scale * w[lane + 128]);
}

// ---------------- bf16 MFMA GEMM, operand-swapped for packed stores -------------
// C[M,N] = X[M,K] * W[N,K]^T. W feeds MFMA operand-1, X operand-2 =>
// D row (q*4+reg) spans N, D col (lane&15) spans M: each lane holds 4 consecutive
// output columns of one data row -> ushort4/float4 packed stores.
// Block 256 thr = 4 waves; wave computes 64 rows x 64 cols.
// Grid: (ceil(N/64), ceil(M/256)). N must be a multiple of 16.
// If splitN>0 (multiple of 16): cols >= splitN go raw fp32 to C2.
template<int K>
__global__ __launch_bounds__(256, 2) void gemm_bf_t(
    const unsigned short* __restrict__ X, int ldx,
    const unsigned short* __restrict__ W, int ldw,
    float* __restrict__ C, int ldc,
    unsigned short* __restrict__ Cbf, int ldcbf,
    float* __restrict__ C2, int ldc2, int splitN,
    const float* __restrict__ bias,
    int M, int N, int act)
{
    int w    = threadIdx.x >> 6;
    int lane = threadIdx.x & 63;
    int q    = lane >> 4;
    int r    = lane & 15;
    int bm   = blockIdx.y * 256 + w * 64;
    int bn   = blockIdx.x * 64;

    const unsigned short* Xp[4];
    const unsigned short* Wp[4];
    #pragma unroll
    for (int f = 0; f < 4; ++f) {
        int xrow = bm + f * 16 + r; if (xrow > M - 1) xrow = M - 1;
        Xp[f] = X + (size_t)xrow * ldx + q * 8;
        int n = bn + f * 16 + r;    if (n > N - 1) n = N - 1;
        Wp[f] = W + (size_t)n * ldw + q * 8;
    }

    f4 acc[4][4];   // [f: N-strip][c: M-strip]
    #pragma unroll
    for (int f = 0; f < 4; ++f)
        #pragma unroll
        for (int c = 0; c < 4; ++c) acc[f][c] = {0.f, 0.f, 0.f, 0.f};

    #pragma unroll
    for (int k0 = 0; k0 < K; k0 += 32) {
        s8b wf[4], xf[4];
        #pragma unroll
        for (int f = 0; f < 4; ++f) {
            wf[f] = *(const s8b*)(Wp[f] + k0);
            xf[f] = *(const s8b*)(Xp[f] + k0);
        }
        #pragma unroll
        for (int f = 0; f < 4; ++f)
            #pragma unroll
            for (int c = 0; c < 4; ++c)
                acc[f][c] = __builtin_amdgcn_mfma_f32_16x16x32_bf16(wf[f], xf[c], acc[f][c], 0, 0, 0);
    }

    // D layout: row (q*4+reg) = n within frag f; col (r) = m within strip c.
    #pragma unroll
    for (int f = 0; f < 4; ++f) {
        int n0 = bn + f * 16 + q * 4;     // 4 consecutive output cols
        if (n0 >= N) continue;            // frag-granular (N mult of 16)
        bool isC2 = (splitN > 0 && n0 >= splitN);
        float4 bi = {0.f, 0.f, 0.f, 0.f};
        if (bias && !isC2) bi = *(const float4*)(bias + n0);
        #pragma unroll
        for (int c = 0; c < 4; ++c) {
            int gm = bm + c * 16 + r;
            if (gm >= M) continue;
            f4 v = acc[f][c];
            if (isC2) {
                float4 o = {v[0], v[1], v[2], v[3]};
                *(float4*)&C2[(size_t)gm * ldc2 + (n0 - splitN)] = o;
            } else {
                v[0] += bi.x; v[1] += bi.y; v[2] += bi.z; v[3] += bi.w;
                if (act == 1) {
                    #pragma unroll
                    for (int e = 0; e < 4; ++e)
                        v[e] = fmaxf(v[e], 0.f) + __logf(1.f + __expf(-fabsf(v[e])));
                }
                if (C) {
                    float4 o = {v[0], v[1], v[2], v[3]};
                    *(float4*)&C[(size_t)gm * ldc + n0] = o;
                }
                if (Cbf) {
                    ushort4 o = {f2bf(v[0]), f2bf(v[1]), f2bf(v[2]), f2bf(v[3])};
                    *(ushort4*)&Cbf[(size_t)gm * ldcbf + n0] = o;
                }
            }
        }
    }
}

// ---------------- causal depthwise conv (width 4) + silu, 4 channels/thread -------
__global__ __launch_bounds__(256) void conv_silu_kernel(
    const unsigned short* __restrict__ xzbf, const float* __restrict__ cw,
    const float* __restrict__ cb, unsigned short* __restrict__ xcbf, int total4)
{
    int idx = blockIdx.x * 256 + threadIdx.x;
    if (idx >= total4) return;
    int d4 = (idx % (DI / 4)) * 4;
    int bl = idx / (DI / 4);
    int l  = bl % L_;
    float acc[4];
    #pragma unroll
    for (int c = 0; c < 4; ++c) acc[c] = cb[d4 + c];
    #pragma unroll
    for (int k = 0; k < 4; ++k) {
        int ls = l + k - 3;
        if (ls >= 0) {
            ushort4 xv = *(const ushort4*)(xzbf + (size_t)(bl - l + ls) * (2 * DI) + d4);
            acc[0] = fmaf(cw[(d4 + 0) * 4 + k], bf2f(xv.x), acc[0]);
            acc[1] = fmaf(cw[(d4 + 1) * 4 + k], bf2f(xv.y), acc[1]);
            acc[2] = fmaf(cw[(d4 + 2) * 4 + k], bf2f(xv.z), acc[2]);
            acc[3] = fmaf(cw[(d4 + 3) * 4 + k], bf2f(xv.w), acc[3]);
        }
    }
    ushort4 out;
    out.x = f2bf(acc[0] / (1.f + __expf(-acc[0])));
    out.y = f2bf(acc[1] / (1.f + __expf(-acc[1])));
    out.z = f2bf(acc[2] / (1.f + __expf(-acc[2])));
    out.w = f2bf(acc[3] / (1.f + __expf(-acc[3])));
    *(ushort4*)(xcbf + (size_t)bl * DI + d4) = out;
}

// ---------------- scan pass 1: per-segment transition (P, h_local) ----------------
__global__ __launch_bounds__(64) void scan1_kernel(
    const unsigned short* __restrict__ dt,
    const unsigned short* __restrict__ xcbf,
    const float* __restrict__ dbl,
    const float* __restrict__ A_log,
    float* __restrict__ Hbuf)
{
    int j = blockIdx.x % 7;
    int t = blockIdx.x / 7;
    int b = t / 6;
    int d = (t % 6) * 64 + threadIdx.x;
    f16v Av, hv, Pv;
    #pragma unroll
    for (int s = 0; s < 16; ++s) { Av[s] = -expf(A_log[d * 16 + s]); hv[s] = 0.f; Pv[s] = 1.f; }

    size_t base = (size_t)b * L_;
    const unsigned short* dtp = dt + base * DI + d;
    const unsigned short* xcp = xcbf + base * DI + d;
    const float* bp = dbl + base * 32;
    int l0 = j * SEGLEN;
    int lend = l0 + SEGLEN;

    float dtv[4], xcv[4];
    #pragma unroll
    for (int i = 0; i < 4; ++i) {
        dtv[i] = bf2f(dtp[(size_t)(l0 + i) * DI]);
        xcv[i] = bf2f(xcp[(size_t)(l0 + i) * DI]);
    }
    f16v B0, B1;
    #pragma unroll
    for (int s2 = 0; s2 < 16; ++s2) { B0[s2] = bp[(size_t)l0 * 32 + s2]; B1[s2] = bp[(size_t)(l0 + 1) * 32 + s2]; }

#define S1_BODY(dt_, xc_, Bv)                                            \
    { float coef = (dt_) * (xc_);                                        \
      _Pragma("unroll")                                                  \
      for (int s = 0; s < 16; ++s) {                                     \
          float dA = __expf((dt_) * Av[s]);                              \
          hv[s] = fmaf(hv[s], dA, coef * Bv[s]);                         \
          Pv[s] *= dA; } }
#define S1_PF_B(Bv, lq)                                                  \
    if ((lq) < lend) { _Pragma("unroll")                                 \
      for (int s2 = 0; s2 < 16; ++s2) Bv[s2] = bp[(size_t)(lq) * 32 + s2]; }
#define S1_PF_S(i_, lq)                                                  \
    if ((lq) < lend) { dtv[i_] = bf2f(dtp[(size_t)(lq) * DI]);           \
      xcv[i_] = bf2f(xcp[(size_t)(lq) * DI]); }

    for (int l = l0; l < lend; l += 4) {
        S1_BODY(dtv[0], xcv[0], B0); S1_PF_B(B0, l + 2); S1_PF_S(0, l + 4);
        if (l + 1 < lend) { S1_BODY(dtv[1], xcv[1], B1); S1_PF_B(B1, l + 3); S1_PF_S(1, l + 5); }
        if (l + 2 < lend) { S1_BODY(dtv[2], xcv[2], B0); S1_PF_B(B0, l + 4); S1_PF_S(2, l + 6); }
        if (l + 3 < lend) { S1_BODY(dtv[3], xcv[3], B1); S1_PF_B(B1, l + 5); S1_PF_S(3, l + 7); }
    }
    float* Hp = Hbuf + (size_t)blockIdx.x * 2048 + threadIdx.x;
    #pragma unroll
    for (int s = 0; s < 16; ++s) { Hp[s * 64] = Pv[s]; Hp[(16 + s) * 64] = hv[s]; }
}

// ---------------- scan pass 2: compose h_start, scan segment, emit y ----------------
__global__ __launch_bounds__(64) void scan2_kernel(
    const unsigned short* __restrict__ dt,
    const unsigned short* __restrict__ xcbf,
    const unsigned short* __restrict__ xzbf,
    const float* __restrict__ dbl,
    const float* __restrict__ A_log,
    const float* __restrict__ Dp,
    const float* __restrict__ Hbuf,
    unsigned short* __restrict__ ybf)
{
    int j = blockIdx.x & 7;
    int t = blockIdx.x >> 3;
    int b = t / 6;
    int d = (t % 6) * 64 + threadIdx.x;
    f16v Av, hv;
    #pragma unroll
    for (int s = 0; s < 16; ++s) { Av[s] = -expf(A_log[d * 16 + s]); hv[s] = 0.f; }
    float Dval = Dp[d];

    const float* Hp = Hbuf + (size_t)t * 7 * 2048 + threadIdx.x;
    for (int k = 0; k < j; ++k) {
        const float* hp = Hp + (size_t)k * 2048;
        #pragma unroll
        for (int s = 0; s < 16; ++s)
            hv[s] = fmaf(hp[s * 64], hv[s], hp[(16 + s) * 64]);
    }

    size_t base = (size_t)b * L_;
    const unsigned short* dtp = dt + base * DI + d;
    const unsigned short* xcp = xcbf + base * DI + d;
    const unsigned short* zp  = xzbf + base * (2 * DI) + DI + d;
    const float* bcp = dbl + base * 32;
    unsigned short* yp = ybf + base * DI + d;
    int l0 = j * SEGLEN;
    int lend = l0 + SEGLEN; if (lend > L_) lend = L_;

    float dtv[4], xcv[4], zv[4];
    #pragma unroll
    for (int i = 0; i < 4; ++i) {
        dtv[i] = bf2f(dtp[(size_t)(l0 + i) * DI]);
        xcv[i] = bf2f(xcp[(size_t)(l0 + i) * DI]);
        zv[i]  = bf2f(zp[(size_t)(l0 + i) * (2 * DI)]);
    }
    f16v B0, C0, B1, C1;
    #pragma unroll
    for (int s2 = 0; s2 < 16; ++s2) {
        B0[s2] = bcp[(size_t)l0 * 32 + s2];       C0[s2] = bcp[(size_t)l0 * 32 + 16 + s2];
        B1[s2] = bcp[(size_t)(l0 + 1) * 32 + s2]; C1[s2] = bcp[(size_t)(l0 + 1) * 32 + 16 + s2];
    }

#define S2_BODY(dt_, xc_, z_, Bv, Cv, lcur)                              \
    { float coef = (dt_) * (xc_); float y = 0.f;                         \
      _Pragma("unroll")                                                  \
      for (int s = 0; s < 16; ++s) {                                     \
          float dA = __expf((dt_) * Av[s]);                              \
          hv[s] = fmaf(hv[s], dA, coef * Bv[s]);                         \
          y = fmaf(hv[s], Cv[s], y); }                                   \
      float yv = fmaf(Dval, (xc_), y);                                   \
      float sg = 1.f / (1.f + __expf(-(z_)));                            \
      yp[(size_t)(lcur) * DI] = f2bf(yv * ((z_) * sg)); }
#define S2_PF_BC(Bv, Cv, lq)                                             \
    if ((lq) < lend) { _Pragma("unroll")                                 \
      for (int s2 = 0; s2 < 16; ++s2) {                                  \
          Bv[s2] = bcp[(size_t)(lq) * 32 + s2];                          \
          Cv[s2] = bcp[(size_t)(lq) * 32 + 16 + s2]; } }
#define S2_PF_S(i_, lq)                                                  \
    if ((lq) < lend) { dtv[i_] = bf2f(dtp[(size_t)(lq) * DI]);           \
      xcv[i_] = bf2f(xcp[(size_t)(lq) * DI]);                            \
      zv[i_]  = bf2f(zp[(size_t)(lq) * (2 * DI)]); }

    for (int l = l0; l < lend; l += 4) {
        S2_BODY(dtv[0], xcv[0], zv[0], B0, C0, l); S2_PF_BC(B0, C0, l + 2); S2_PF_S(0, l + 4);
        if (l + 1 < lend) { S2_BODY(dtv[1], xcv[1], zv[1], B1, C1, l + 1); S2_PF_BC(B1, C1, l + 3); S2_PF_S(1, l + 5); }
        if (l + 2 < lend) { S2_BODY(dtv[2], xcv[2], zv[2], B0, C0, l + 2); S2_PF_BC(B0, C0, l + 4); S2_PF_S(2, l + 6); }
        if (l + 3 < lend) { S2_BODY(dtv[3], xcv[3], zv[3], B1, C1, l + 3); S2_PF_BC(B1, C1, l + 5); S2_PF_S(3, l + 7); }
    }
}

// ---------------- final rms on cls row only ----------------
__global__ __launch_bounds__(64) void final_kernel(
    const float* __restrict__ hidden, const float* __restrict__ residual,
    const float* __restrict__ wf, float* __restrict__ v_sem)
{
    int b = blockIdx.x;
    int lane = threadIdx.x;
    size_t row = (size_t)b * L_ + 400;
    const float* hr = hidden + row * DM;
    const float* rr = residual + row * DM;
    float x0 = hr[lane] + rr[lane];
    float x1 = hr[lane + 64] + rr[lane + 64];
    float x2 = hr[lane + 128] + rr[lane + 128];
    float ss = x0 * x0 + x1 * x1 + x2 * x2;
    #pragma unroll
    for (int off = 32; off > 0; off >>= 1) ss += __shfl_down(ss, off);
    ss = __shfl(ss, 0);
    float scale = rsqrtf(ss / (float)DM + 1e-5f);
    v_sem[b * DM + lane]       = x0 * scale * wf[lane];
    v_sem[b * DM + lane + 64]  = x1 * scale * wf[lane + 64];
    v_sem[b * DM + lane + 128] = x2 * scale * wf[lane + 128];
}

// ---------------- tiny MLPs + head ----------------
__global__ __launch_bounds__(256) void mlp1_kernel(
    const float* __restrict__ pl, const float* __restrict__ iat,
    const float* __restrict__ w, const float* __restrict__ bias,
    float* __restrict__ out)
{
    int idx = blockIdx.x * 256 + threadIdx.x;
    if (idx >= 128 * 128) return;
    int b = idx / 128, j = idx % 128;
    float acc = bias[j];
    const float* wr = w + j * 200;
    const float* pr = pl + b * 100;
    const float* ir = iat + b * 100;
    for (int k = 0; k < 100; ++k) acc = fmaf(pr[k], wr[k], acc);
    for (int k = 0; k < 100; ++k) acc = fmaf(ir[k], wr[100 + k], acc);
    out[idx] = fmaxf(acc, 0.f);
}

__global__ __launch_bounds__(256) void mlp2_kernel(
    const float* __restrict__ h1, const float* __restrict__ w,
    const float* __restrict__ bias, float* __restrict__ out)
{
    int idx = blockIdx.x * 256 + threadIdx.x;
    if (idx >= 128 * 128) return;
    int b = idx / 128, j = idx % 128;
    float acc = bias[j];
    const float* wr = w + j * 128;
    const float* hr = h1 + b * 128;
    for (int k = 0; k < 128; ++k) acc = fmaf(hr[k], wr[k], acc);
    out[idx] = acc;
}

__global__ __launch_bounds__(256) void head_kernel(
    const float* __restrict__ v_sem, const float* __restrict__ v_stat,
    const float* __restrict__ w, const float* __restrict__ bias,
    float* __restrict__ out)
{
    int idx = blockIdx.x * 256 + threadIdx.x;
    if (idx >= 128 * 20) return;
    int b = idx / 20, o = idx % 20;
    float acc = bias[o];
    const float* wr = w + o * 320;
    const float* vs = v_sem + b * DM;
    const float* vt = v_stat + b * 128;
    for (int k = 0; k < DM; ++k)  acc = fmaf(vs[k], wr[k], acc);
    for (int k = 0; k < 128; ++k) acc = fmaf(vt[k], wr[DM + k], acc);
    out[idx] = acc;
}

extern "C" void kernel_launch(void* const* d_in, const int* in_sizes, int n_in,
                              void* d_out, int out_size, void* d_ws, size_t ws_size,
                              hipStream_t stream)
{
    const float* imgs       = (const float*)d_in[0];
    const float* pl         = (const float*)d_in[1];
    const float* iat        = (const float*)d_in[2];
    const float* pe_w       = (const float*)d_in[3];
    const float* pe_b       = (const float*)d_in[4];
    const float* cls_token  = (const float*)d_in[5];
    const float* pos_embed  = (const float*)d_in[6];
    const float* norm_ws    = (const float*)d_in[7];
    const float* in_proj_ws = (const float*)d_in[8];
    const float* conv_ws    = (const float*)d_in[9];
    const float* conv_bs    = (const float*)d_in[10];
    const float* x_proj_ws  = (const float*)d_in[11];
    const float* dt_proj_ws = (const float*)d_in[12];
    const float* dt_proj_bs = (const float*)d_in[13];
    const float* A_logs     = (const float*)d_in[14];
    const float* Ds         = (const float*)d_in[15];
    const float* out_proj_ws= (const float*)d_in[16];
    const float* norm_f_w   = (const float*)d_in[17];
    const float* mlp1_w     = (const float*)d_in[18];
    const float* mlp1_b     = (const float*)d_in[19];
    const float* mlp2_w     = (const float*)d_in[20];
    const float* mlp2_b     = (const float*)d_in[21];
    const float* head_w     = (const float*)d_in[22];
    const float* head_b     = (const float*)d_in[23];

    float* ws = (float*)d_ws;
    size_t off = 0;
    float* v_sem  = ws + off; off += 128 * DM;
    float* h1     = ws + off; off += 128 * 128;
    float* v_stat = ws + off; off += 128 * 128;
    unsigned short* inw_bf = (unsigned short*)(ws + off); off += (size_t)4 * 768 * DM / 2;
    unsigned short* ow_bf  = (unsigned short*)(ws + off); off += (size_t)4 * DM * DI / 2;
    unsigned short* xdtw   = (unsigned short*)(ws + off); off += (size_t)4 * 416 * DI / 2;
    float* chunkbuf = ws + off;
    size_t small_floats = off;

    // per-b floats: rows(401)*[hidden 192 + residual 192 + dtbf 192 + dbl 32 +
    //   nbf 96 + xzbf 384 + xcbf 192 + ybf 192] + Hbuf 6*7*2048
    const size_t per_b = (size_t)L_ * (192 + 192 + 192 + 32 + 96 + 384 + 192 + 192)
                       + (size_t)6 * 7 * 2048;
    size_t avail = ws_size / sizeof(float);
    avail = (avail > small_floats) ? (avail - small_floats) : 0;
    int Bc = (int)(avail / per_b);
    if (Bc > B_) Bc = B_;
    if (Bc < 1) Bc = 1;

    // weight prep (once per call; ws re-poisoned before every timed call)
    convw_kernel<<<512, 256, 0, stream>>>(in_proj_ws, inw_bf, 4 * 768 * DM);
    convw_kernel<<<512, 256, 0, stream>>>(out_proj_ws, ow_bf, 4 * DM * DI);
    build_xdtw_kernel<<<(4 * 416 * 384 + 255) / 256, 256, 0, stream>>>(x_proj_ws, dt_proj_ws, xdtw);

    for (int b0 = 0; b0 < B_; b0 += Bc) {
        int bc = (B_ - b0 < Bc) ? (B_ - b0) : Bc;
        int rows = bc * L_;
        float* hidden   = chunkbuf;
        float* residual = hidden + (size_t)rows * DM;
        float* dbl      = residual + (size_t)rows * DM;            // fp32 B,C [rows][32]
        float* Hbuf     = dbl + (size_t)rows * 32;                 // bc*6*7*2048
        unsigned short* dtbf = (unsigned short*)(Hbuf + (size_t)bc * 6 * 7 * 2048);
        unsigned short* nbf  = dtbf + (size_t)rows * DI;           // [rows][192]
        unsigned short* xzbf = nbf + (size_t)rows * DM;            // [rows][768]
        unsigned short* xcbf = xzbf + (size_t)rows * 2 * DI;       // [rows][384]
        unsigned short* ybf  = xcbf + (size_t)rows * DI;           // [rows][384]

        int gmy = (rows + 255) / 256;

        embed_kernel<<<rows, DM, 0, stream>>>(imgs + (size_t)b0 * 1600,
                                              pe_w, pe_b, cls_token, pos_embed, hidden);

        for (int i = 0; i < 4; ++i) {
            rms_kernel<<<(rows + 3) / 4, 256, 0, stream>>>(
                hidden, residual, nbf, norm_ws + i * DM, i > 0 ? 1 : 0, rows);
            // in_proj -> xzbf (bf16): (rows,192)x(768,192)^T
            gemm_bf_t<192><<<dim3(12, gmy), 256, 0, stream>>>(
                nbf, DM, inw_bf + (size_t)i * 768 * DM, DM,
                nullptr, 0, xzbf, 2 * DI, nullptr, 0, 0,
                nullptr, rows, 2 * DI, 0);
            // conv + silu -> xcbf
            int total4 = rows * (DI / 4);
            conv_silu_kernel<<<(total4 + 255) / 256, 256, 0, stream>>>(
                xzbf, conv_ws + i * DI * 4, conv_bs + i * DI, xcbf, total4);
            // fused x_proj+dt_proj: (rows,384)x(416,384)^T; cols<384 -> softplus dt bf16,
            // cols>=384 -> B,C raw fp32 (ld 32)
            gemm_bf_t<384><<<dim3(7, gmy), 256, 0, stream>>>(
                xcbf, DI, xdtw + (size_t)i * 416 * DI, DI,
                nullptr, 0, dtbf, DI, dbl, 32, DI,
                dt_proj_bs + i * DI, rows, 416, 1);
            // segmented scan
            scan1_kernel<<<bc * 6 * 7, 64, 0, stream>>>(
                dtbf, xcbf, dbl, A_logs + (size_t)i * DI * DSTATE, Hbuf);
            scan2_kernel<<<bc * 6 * 8, 64, 0, stream>>>(
                dtbf, xcbf, xzbf, dbl, A_logs + (size_t)i * DI * DSTATE,
                Ds + i * DI, Hbuf, ybf);
            // out_proj: (rows,384)x(192,384)^T -> hidden fp32
            gemm_bf_t<384><<<dim3(3, gmy), 256, 0, stream>>>(
                ybf, DI, ow_bf + (size_t)i * DM * DI, DI,
                hidden, DM, nullptr, 0, nullptr, 0, 0,
                nullptr, rows, DM, 0);
        }

        final_kernel<<<bc, 64, 0, stream>>>(hidden, residual, norm_f_w,
                                            v_sem + (size_t)b0 * DM);
    }

    mlp1_kernel<<<64, 256, 0, stream>>>(pl, iat, mlp1_w, mlp1_b, h1);
    mlp2_kernel<<<64, 256, 0, stream>>>(h1, mlp2_w, mlp2_b, v_stat);
    head_kernel<<<10, 256, 0, stream>>>(v_sem, v_stat, head_w, head_b, (float*)d_out);
}

// Round 7
// 2475.656 us; speedup vs baseline: 1.3003x; 1.1478x over previous
//
#include <hip/hip_runtime.h>
#include <math.h>

#define B_   128
#define L_   401
#define DM   192
#define DI   384
#define DSTATE 16
#define DTR  12
#define SEG  8
#define SEGLEN 51    // ceil(401/8); segments 0..6 full 51, segment 7 = 44

typedef __attribute__((ext_vector_type(8))) short s8b;     // 8 bf16
typedef __attribute__((ext_vector_type(4))) float f4;
typedef __attribute__((ext_vector_type(16))) float f16v;

__device__ __forceinline__ unsigned short f2bf(float x) {
    unsigned int u = __builtin_bit_cast(unsigned int, x);
    unsigned int r = (u + 0x7fffu + ((u >> 16) & 1u)) >> 16;
    return (unsigned short)r;
}
__device__ __forceinline__ float bf2f(unsigned short x) {
    unsigned int u = ((unsigned int)x) << 16;
    return __builtin_bit_cast(float, u);
}

// ---------------- weight fp32 -> bf16 ----------------
__global__ __launch_bounds__(256) void convw_kernel(
    const float* __restrict__ src, unsigned short* __restrict__ dst, int total)
{
    for (int idx = blockIdx.x * 256 + threadIdx.x; idx < total; idx += gridDim.x * 256)
        dst[idx] = f2bf(src[idx]);
}

// ---------------- transpose conv weights: cwT[i][k][d] = cw[i][d][k] ----------
__global__ __launch_bounds__(256) void convcw_kernel(
    const float* __restrict__ cw, float* __restrict__ cwT)
{
    int idx = blockIdx.x * 256 + threadIdx.x;
    if (idx >= 4 * 4 * DI) return;
    int d = idx % DI;
    int k = (idx / DI) % 4;
    int i = idx / (4 * DI);
    cwT[idx] = cw[((size_t)i * DI + d) * 4 + k];
}

// ---------------- build fused x_proj+dt_proj weight: [4][416][384] bf16 --------
__global__ __launch_bounds__(256) void build_xdtw_kernel(
    const float* __restrict__ xp_w, const float* __restrict__ dt_w,
    unsigned short* __restrict__ out)
{
    int idx = blockIdx.x * 256 + threadIdx.x;
    if (idx >= 4 * 416 * 384) return;
    int k  = idx % 384;
    int rr = (idx / 384) % 416;
    int i  = idx / (384 * 416);
    const float* xp = xp_w + (size_t)i * 44 * 384;
    float v;
    if (rr < 384) {
        const float* dw = dt_w + (size_t)i * 384 * 12 + rr * 12;
        v = 0.f;
        #pragma unroll
        for (int r = 0; r < 12; ++r) v = fmaf(dw[r], xp[r * 384 + k], v);
    } else {
        v = xp[(12 + (rr - 384)) * 384 + k];
    }
    out[idx] = f2bf(v);
}

// ---------------- embed -> residual ----------------
__global__ void embed_kernel(const float* __restrict__ imgs,
                             const float* __restrict__ pe_w,
                             const float* __restrict__ pe_b,
                             const float* __restrict__ cls_token,
                             const float* __restrict__ pos_embed,
                             float* __restrict__ x)
{
    int row = blockIdx.x;
    int l = row % L_;
    int b = row / L_;
    int d = threadIdx.x;
    float v;
    if (l < 400) {
        const float* f = imgs + (size_t)b * 1600 + (size_t)l * 4;
        const float* pw = pe_w + d * 4;
        v = pe_b[d];
        v = fmaf(f[0], pw[0], v);
        v = fmaf(f[1], pw[1], v);
        v = fmaf(f[2], pw[2], v);
        v = fmaf(f[3], pw[3], v);
        v += pos_embed[l * DM + d];
    } else {
        v = cls_token[d] + pos_embed[400 * DM + d];
    }
    x[(size_t)row * DM + d] = v;
}

// ---------------- standalone rms (layer-0 input): nbf = rms(residual)*w ---------
__global__ __launch_bounds__(256) void rms_kernel(
    const float* __restrict__ residual, unsigned short* __restrict__ nbf,
    const float* __restrict__ w, int nrows)
{
    int wv   = threadIdx.x >> 6;
    int lane = threadIdx.x & 63;
    int row  = blockIdx.x * 4 + wv;
    if (row >= nrows) return;
    const float* rr = residual + (size_t)row * DM;
    float x0 = rr[lane], x1 = rr[lane + 64], x2 = rr[lane + 128];
    float ss = x0 * x0 + x1 * x1 + x2 * x2;
    #pragma unroll
    for (int off = 32; off > 0; off >>= 1) ss += __shfl_down(ss, off);
    ss = __shfl(ss, 0);
    float scale = rsqrtf(ss / (float)DM + 1e-5f);
    unsigned short* nr = nbf + (size_t)row * DM;
    nr[lane]       = f2bf(x0 * scale * w[lane]);
    nr[lane + 64]  = f2bf(x1 * scale * w[lane + 64]);
    nr[lane + 128] = f2bf(x2 * scale * w[lane + 128]);
}

// ---------------- bf16 MFMA GEMM, operand-swapped for packed stores -------------
// C[M,N] = X[M,K] * W[N,K]^T. W op-1, X op-2 => lane holds 4 consecutive cols of
// one data row. Block 256 = 4 waves; wave: 64 rows x 64 cols.
// Grid: (ceil(N/64), ceil(M/256)). If splitN>0: cols >= splitN raw fp32 to C2.
template<int K>
__global__ __launch_bounds__(256, 2) void gemm_bf_t(
    const unsigned short* __restrict__ X, int ldx,
    const unsigned short* __restrict__ W, int ldw,
    float* __restrict__ C, int ldc,
    unsigned short* __restrict__ Cbf, int ldcbf,
    float* __restrict__ C2, int ldc2, int splitN,
    const float* __restrict__ bias,
    int M, int N, int act)
{
    int w    = threadIdx.x >> 6;
    int lane = threadIdx.x & 63;
    int q    = lane >> 4;
    int r    = lane & 15;
    int bm   = blockIdx.y * 256 + w * 64;
    int bn   = blockIdx.x * 64;

    const unsigned short* Xp[4];
    const unsigned short* Wp[4];
    #pragma unroll
    for (int f = 0; f < 4; ++f) {
        int xrow = bm + f * 16 + r; if (xrow > M - 1) xrow = M - 1;
        Xp[f] = X + (size_t)xrow * ldx + q * 8;
        int n = bn + f * 16 + r;    if (n > N - 1) n = N - 1;
        Wp[f] = W + (size_t)n * ldw + q * 8;
    }

    f4 acc[4][4];   // [f: N-strip][c: M-strip]
    #pragma unroll
    for (int f = 0; f < 4; ++f)
        #pragma unroll
        for (int c = 0; c < 4; ++c) acc[f][c] = {0.f, 0.f, 0.f, 0.f};

    #pragma unroll
    for (int k0 = 0; k0 < K; k0 += 32) {
        s8b wf[4], xf[4];
        #pragma unroll
        for (int f = 0; f < 4; ++f) {
            wf[f] = *(const s8b*)(Wp[f] + k0);
            xf[f] = *(const s8b*)(Xp[f] + k0);
        }
        #pragma unroll
        for (int f = 0; f < 4; ++f)
            #pragma unroll
            for (int c = 0; c < 4; ++c)
                acc[f][c] = __builtin_amdgcn_mfma_f32_16x16x32_bf16(wf[f], xf[c], acc[f][c], 0, 0, 0);
    }

    #pragma unroll
    for (int f = 0; f < 4; ++f) {
        int n0 = bn + f * 16 + q * 4;
        if (n0 >= N) continue;
        bool isC2 = (splitN > 0 && n0 >= splitN);
        float4 bi = {0.f, 0.f, 0.f, 0.f};
        if (bias && !isC2) bi = *(const float4*)(bias + n0);
        #pragma unroll
        for (int c = 0; c < 4; ++c) {
            int gm = bm + c * 16 + r;
            if (gm >= M) continue;
            f4 v = acc[f][c];
            if (isC2) {
                float4 o = {v[0], v[1], v[2], v[3]};
                *(float4*)&C2[(size_t)gm * ldc2 + (n0 - splitN)] = o;
            } else {
                v[0] += bi.x; v[1] += bi.y; v[2] += bi.z; v[3] += bi.w;
                if (act == 1) {
                    #pragma unroll
                    for (int e = 0; e < 4; ++e)
                        v[e] = fmaxf(v[e], 0.f) + __logf(1.f + __expf(-fabsf(v[e])));
                }
                if (C) {
                    float4 o = {v[0], v[1], v[2], v[3]};
                    *(float4*)&C[(size_t)gm * ldc + n0] = o;
                }
                if (Cbf) {
                    ushort4 o = {f2bf(v[0]), f2bf(v[1]), f2bf(v[2]), f2bf(v[3])};
                    *(ushort4*)&Cbf[(size_t)gm * ldcbf + n0] = o;
                }
            }
        }
    }
}

// ---------------- out_proj + residual update + fused rms -------------------------
// residual[M,192] += ybf @ W^T; if nbf: nbf = rms(residual)*normw.
// Block 256 = 4 waves; wave: 32 rows x full 192 cols (3 tiles x 4 frags in regs).
// Grid: (1, M/128). M must be multiple of 128.
__global__ __launch_bounds__(256, 2) void gemm_out_rms(
    const unsigned short* __restrict__ X, int ldx,
    const unsigned short* __restrict__ W, int ldw,   // [192][384]
    float* __restrict__ residual,
    unsigned short* __restrict__ nbf,
    const float* __restrict__ normw,
    int M)
{
    int w    = threadIdx.x >> 6;
    int lane = threadIdx.x & 63;
    int q    = lane >> 4;
    int r    = lane & 15;
    int bm   = blockIdx.y * 128 + w * 32;

    const unsigned short* Xp[2];
    #pragma unroll
    for (int c = 0; c < 2; ++c) {
        int xrow = bm + c * 16 + r; if (xrow > M - 1) xrow = M - 1;
        Xp[c] = X + (size_t)xrow * ldx + q * 8;
    }
    const unsigned short* Wp[12];
    #pragma unroll
    for (int f = 0; f < 12; ++f)
        Wp[f] = W + (size_t)(f * 16 + r) * ldw + q * 8;

    f4 acc[12][2];
    #pragma unroll
    for (int f = 0; f < 12; ++f)
        #pragma unroll
        for (int c = 0; c < 2; ++c) acc[f][c] = {0.f, 0.f, 0.f, 0.f};

    #pragma unroll
    for (int k0 = 0; k0 < 384; k0 += 32) {
        s8b xf[2], wf[12];
        #pragma unroll
        for (int c = 0; c < 2; ++c) xf[c] = *(const s8b*)(Xp[c] + k0);
        #pragma unroll
        for (int f = 0; f < 12; ++f) wf[f] = *(const s8b*)(Wp[f] + k0);
        #pragma unroll
        for (int f = 0; f < 12; ++f)
            #pragma unroll
            for (int c = 0; c < 2; ++c)
                acc[f][c] = __builtin_amdgcn_mfma_f32_16x16x32_bf16(wf[f], xf[c], acc[f][c], 0, 0, 0);
    }

    // epilogue: lane holds, for rows m = bm+c*16+r (c=0,1), cols n = f*16+q*4+e.
    #pragma unroll
    for (int c = 0; c < 2; ++c) {
        int m = bm + c * 16 + r;
        bool valid = (m < M);
        float* rrow = residual + (size_t)(valid ? m : 0) * DM;
        f4 vv[12];
        float ss = 0.f;
        #pragma unroll
        for (int f = 0; f < 12; ++f) {
            int n0 = f * 16 + q * 4;
            float4 res = valid ? *(const float4*)(rrow + n0) : float4{0.f,0.f,0.f,0.f};
            f4 v = acc[f][c];
            v[0] += res.x; v[1] += res.y; v[2] += res.z; v[3] += res.w;
            vv[f] = v;
            ss += v[0]*v[0] + v[1]*v[1] + v[2]*v[2] + v[3]*v[3];
        }
        ss += __shfl_xor(ss, 16);
        ss += __shfl_xor(ss, 32);
        float scale = rsqrtf(ss / (float)DM + 1e-5f);
        if (valid) {
            unsigned short* nrow = nbf ? nbf + (size_t)m * DM : nullptr;
            #pragma unroll
            for (int f = 0; f < 12; ++f) {
                int n0 = f * 16 + q * 4;
                f4 v = vv[f];
                float4 o = {v[0], v[1], v[2], v[3]};
                *(float4*)(rrow + n0) = o;
                if (nrow) {
                    float4 nw = *(const float4*)(normw + n0);
                    ushort4 ob = {f2bf(v[0]*scale*nw.x), f2bf(v[1]*scale*nw.y),
                                  f2bf(v[2]*scale*nw.z), f2bf(v[3]*scale*nw.w)};
                    *(ushort4*)(nrow + n0) = ob;
                }
            }
        }
    }
}

// ---------------- causal depthwise conv (width 4) + silu, transposed weights -----
__global__ __launch_bounds__(256) void conv_silu_kernel(
    const unsigned short* __restrict__ xzbf, const float* __restrict__ cwT,
    const float* __restrict__ cb, unsigned short* __restrict__ xcbf, int total4)
{
    int idx = blockIdx.x * 256 + threadIdx.x;
    if (idx >= total4) return;
    int d4 = (idx % (DI / 4)) * 4;
    int bl = idx / (DI / 4);
    int l  = bl % L_;
    float4 cbv = *(const float4*)(cb + d4);
    float acc[4] = {cbv.x, cbv.y, cbv.z, cbv.w};
    #pragma unroll
    for (int k = 0; k < 4; ++k) {
        int ls = l + k - 3;
        if (ls >= 0) {
            float4 wk = *(const float4*)(cwT + k * DI + d4);
            ushort4 xv = *(const ushort4*)(xzbf + (size_t)(bl - l + ls) * (2 * DI) + d4);
            acc[0] = fmaf(wk.x, bf2f(xv.x), acc[0]);
            acc[1] = fmaf(wk.y, bf2f(xv.y), acc[1]);
            acc[2] = fmaf(wk.z, bf2f(xv.z), acc[2]);
            acc[3] = fmaf(wk.w, bf2f(xv.w), acc[3]);
        }
    }
    ushort4 out;
    out.x = f2bf(acc[0] / (1.f + __expf(-acc[0])));
    out.y = f2bf(acc[1] / (1.f + __expf(-acc[1])));
    out.z = f2bf(acc[2] / (1.f + __expf(-acc[2])));
    out.w = f2bf(acc[3] / (1.f + __expf(-acc[3])));
    *(ushort4*)(xcbf + (size_t)bl * DI + d4) = out;
}

// ---------------- scan pass 1: per-segment transition (P, h_local) ----------------
__global__ __launch_bounds__(64) void scan1_kernel(
    const unsigned short* __restrict__ dt,
    const unsigned short* __restrict__ xcbf,
    const float* __restrict__ dbl,
    const float* __restrict__ A_log,
    float* __restrict__ Hbuf)
{
    int j = blockIdx.x % 7;
    int t = blockIdx.x / 7;
    int b = t / 6;
    int d = (t % 6) * 64 + threadIdx.x;
    f16v Av, hv, Pv;
    #pragma unroll
    for (int s = 0; s < 16; ++s) { Av[s] = -expf(A_log[d * 16 + s]); hv[s] = 0.f; Pv[s] = 1.f; }

    size_t base = (size_t)b * L_;
    const unsigned short* dtp = dt + base * DI + d;
    const unsigned short* xcp = xcbf + base * DI + d;
    const float* bp = dbl + base * 32;
    int l0 = j * SEGLEN;
    int lend = l0 + SEGLEN;

    float dtv[4], xcv[4];
    #pragma unroll
    for (int i = 0; i < 4; ++i) {
        dtv[i] = bf2f(dtp[(size_t)(l0 + i) * DI]);
        xcv[i] = bf2f(xcp[(size_t)(l0 + i) * DI]);
    }
    f16v B0, B1;
    #pragma unroll
    for (int s2 = 0; s2 < 16; ++s2) { B0[s2] = bp[(size_t)l0 * 32 + s2]; B1[s2] = bp[(size_t)(l0 + 1) * 32 + s2]; }

#define S1_BODY(dt_, xc_, Bv)                                            \
    { float coef = (dt_) * (xc_);                                        \
      _Pragma("unroll")                                                  \
      for (int s = 0; s < 16; ++s) {                                     \
          float dA = __expf((dt_) * Av[s]);                              \
          hv[s] = fmaf(hv[s], dA, coef * Bv[s]);                         \
          Pv[s] *= dA; } }
#define S1_PF_B(Bv, lq)                                                  \
    if ((lq) < lend) { _Pragma("unroll")                                 \
      for (int s2 = 0; s2 < 16; ++s2) Bv[s2] = bp[(size_t)(lq) * 32 + s2]; }
#define S1_PF_S(i_, lq)                                                  \
    if ((lq) < lend) { dtv[i_] = bf2f(dtp[(size_t)(lq) * DI]);           \
      xcv[i_] = bf2f(xcp[(size_t)(lq) * DI]); }

    for (int l = l0; l < lend; l += 4) {
        S1_BODY(dtv[0], xcv[0], B0); S1_PF_B(B0, l + 2); S1_PF_S(0, l + 4);
        if (l + 1 < lend) { S1_BODY(dtv[1], xcv[1], B1); S1_PF_B(B1, l + 3); S1_PF_S(1, l + 5); }
        if (l + 2 < lend) { S1_BODY(dtv[2], xcv[2], B0); S1_PF_B(B0, l + 4); S1_PF_S(2, l + 6); }
        if (l + 3 < lend) { S1_BODY(dtv[3], xcv[3], B1); S1_PF_B(B1, l + 5); S1_PF_S(3, l + 7); }
    }
    float* Hp = Hbuf + (size_t)blockIdx.x * 2048 + threadIdx.x;
    #pragma unroll
    for (int s = 0; s < 16; ++s) { Hp[s * 64] = Pv[s]; Hp[(16 + s) * 64] = hv[s]; }
}

// ---------------- scan pass 2: compose h_start, scan segment, emit y ----------------
__global__ __launch_bounds__(64) void scan2_kernel(
    const unsigned short* __restrict__ dt,
    const unsigned short* __restrict__ xcbf,
    const unsigned short* __restrict__ xzbf,
    const float* __restrict__ dbl,
    const float* __restrict__ A_log,
    const float* __restrict__ Dp,
    const float* __restrict__ Hbuf,
    unsigned short* __restrict__ ybf)
{
    int j = blockIdx.x & 7;
    int t = blockIdx.x >> 3;
    int b = t / 6;
    int d = (t % 6) * 64 + threadIdx.x;
    f16v Av, hv;
    #pragma unroll
    for (int s = 0; s < 16; ++s) { Av[s] = -expf(A_log[d * 16 + s]); hv[s] = 0.f; }
    float Dval = Dp[d];

    const float* Hp = Hbuf + (size_t)t * 7 * 2048 + threadIdx.x;
    for (int k = 0; k < j; ++k) {
        const float* hp = Hp + (size_t)k * 2048;
        #pragma unroll
        for (int s = 0; s < 16; ++s)
            hv[s] = fmaf(hp[s * 64], hv[s], hp[(16 + s) * 64]);
    }

    size_t base = (size_t)b * L_;
    const unsigned short* dtp = dt + base * DI + d;
    const unsigned short* xcp = xcbf + base * DI + d;
    const unsigned short* zp  = xzbf + base * (2 * DI) + DI + d;
    const float* bcp = dbl + base * 32;
    unsigned short* yp = ybf + base * DI + d;
    int l0 = j * SEGLEN;
    int lend = l0 + SEGLEN; if (lend > L_) lend = L_;

    float dtv[4], xcv[4], zv[4];
    #pragma unroll
    for (int i = 0; i < 4; ++i) {
        dtv[i] = bf2f(dtp[(size_t)(l0 + i) * DI]);
        xcv[i] = bf2f(xcp[(size_t)(l0 + i) * DI]);
        zv[i]  = bf2f(zp[(size_t)(l0 + i) * (2 * DI)]);
    }
    f16v B0, C0, B1, C1;
    #pragma unroll
    for (int s2 = 0; s2 < 16; ++s2) {
        B0[s2] = bcp[(size_t)l0 * 32 + s2];       C0[s2] = bcp[(size_t)l0 * 32 + 16 + s2];
        B1[s2] = bcp[(size_t)(l0 + 1) * 32 + s2]; C1[s2] = bcp[(size_t)(l0 + 1) * 32 + 16 + s2];
    }

#define S2_BODY(dt_, xc_, z_, Bv, Cv, lcur)                              \
    { float coef = (dt_) * (xc_); float y = 0.f;                         \
      _Pragma("unroll")                                                  \
      for (int s = 0; s < 16; ++s) {                                     \
          float dA = __expf((dt_) * Av[s]);                              \
          hv[s] = fmaf(hv[s], dA, coef * Bv[s]);                         \
          y = fmaf(hv[s], Cv[s], y); }                                   \
      float yv = fmaf(Dval, (xc_), y);                                   \
      float sg = 1.f / (1.f + __expf(-(z_)));                            \
      yp[(size_t)(lcur) * DI] = f2bf(yv * ((z_) * sg)); }
#define S2_PF_BC(Bv, Cv, lq)                                             \
    if ((lq) < lend) { _Pragma("unroll")                                 \
      for (int s2 = 0; s2 < 16; ++s2) {                                  \
          Bv[s2] = bcp[(size_t)(lq) * 32 + s2];                          \
          Cv[s2] = bcp[(size_t)(lq) * 32 + 16 + s2]; } }
#define S2_PF_S(i_, lq)                                                  \
    if ((lq) < lend) { dtv[i_] = bf2f(dtp[(size_t)(lq) * DI]);           \
      xcv[i_] = bf2f(xcp[(size_t)(lq) * DI]);                            \
      zv[i_]  = bf2f(zp[(size_t)(lq) * (2 * DI)]); }

    for (int l = l0; l < lend; l += 4) {
        S2_BODY(dtv[0], xcv[0], zv[0], B0, C0, l); S2_PF_BC(B0, C0, l + 2); S2_PF_S(0, l + 4);
        if (l + 1 < lend) { S2_BODY(dtv[1], xcv[1], zv[1], B1, C1, l + 1); S2_PF_BC(B1, C1, l + 3); S2_PF_S(1, l + 5); }
        if (l + 2 < lend) { S2_BODY(dtv[2], xcv[2], zv[2], B0, C0, l + 2); S2_PF_BC(B0, C0, l + 4); S2_PF_S(2, l + 6); }
        if (l + 3 < lend) { S2_BODY(dtv[3], xcv[3], zv[3], B1, C1, l + 3); S2_PF_BC(B1, C1, l + 5); S2_PF_S(3, l + 7); }
    }
}

// ---------------- final rms on cls row (residual already holds hidden+residual) ---
__global__ __launch_bounds__(64) void final_kernel(
    const float* __restrict__ residual,
    const float* __restrict__ wf, float* __restrict__ v_sem)
{
    int b = blockIdx.x;
    int lane = threadIdx.x;
    size_t row = (size_t)b * L_ + 400;
    const float* rr = residual + row * DM;
    float x0 = rr[lane], x1 = rr[lane + 64], x2 = rr[lane + 128];
    float ss = x0 * x0 + x1 * x1 + x2 * x2;
    #pragma unroll
    for (int off = 32; off > 0; off >>= 1) ss += __shfl_down(ss, off);
    ss = __shfl(ss, 0);
    float scale = rsqrtf(ss / (float)DM + 1e-5f);
    v_sem[b * DM + lane]       = x0 * scale * wf[lane];
    v_sem[b * DM + lane + 64]  = x1 * scale * wf[lane + 64];
    v_sem[b * DM + lane + 128] = x2 * scale * wf[lane + 128];
}

// ---------------- tiny MLPs + head ----------------
__global__ __launch_bounds__(256) void mlp1_kernel(
    const float* __restrict__ pl, const float* __restrict__ iat,
    const float* __restrict__ w, const float* __restrict__ bias,
    float* __restrict__ out)
{
    int idx = blockIdx.x * 256 + threadIdx.x;
    if (idx >= 128 * 128) return;
    int b = idx / 128, j = idx % 128;
    float acc = bias[j];
    const float* wr = w + j * 200;
    const float* pr = pl + b * 100;
    const float* ir = iat + b * 100;
    for (int k = 0; k < 100; ++k) acc = fmaf(pr[k], wr[k], acc);
    for (int k = 0; k < 100; ++k) acc = fmaf(ir[k], wr[100 + k], acc);
    out[idx] = fmaxf(acc, 0.f);
}

__global__ __launch_bounds__(256) void mlp2_kernel(
    const float* __restrict__ h1, const float* __restrict__ w,
    const float* __restrict__ bias, float* __restrict__ out)
{
    int idx = blockIdx.x * 256 + threadIdx.x;
    if (idx >= 128 * 128) return;
    int b = idx / 128, j = idx % 128;
    float acc = bias[j];
    const float* wr = w + j * 128;
    const float* hr = h1 + b * 128;
    for (int k = 0; k < 128; ++k) acc = fmaf(hr[k], wr[k], acc);
    out[idx] = acc;
}

__global__ __launch_bounds__(256) void head_kernel(
    const float* __restrict__ v_sem, const float* __restrict__ v_stat,
    const float* __restrict__ w, const float* __restrict__ bias,
    float* __restrict__ out)
{
    int idx = blockIdx.x * 256 + threadIdx.x;
    if (idx >= 128 * 20) return;
    int b = idx / 20, o = idx % 20;
    float acc = bias[o];
    const float* wr = w + o * 320;
    const float* vs = v_sem + b * DM;
    const float* vt = v_stat + b * 128;
    for (int k = 0; k < DM; ++k)  acc = fmaf(vs[k], wr[k], acc);
    for (int k = 0; k < 128; ++k) acc = fmaf(vt[k], wr[DM + k], acc);
    out[idx] = acc;
}

extern "C" void kernel_launch(void* const* d_in, const int* in_sizes, int n_in,
                              void* d_out, int out_size, void* d_ws, size_t ws_size,
                              hipStream_t stream)
{
    const float* imgs       = (const float*)d_in[0];
    const float* pl         = (const float*)d_in[1];
    const float* iat        = (const float*)d_in[2];
    const float* pe_w       = (const float*)d_in[3];
    const float* pe_b       = (const float*)d_in[4];
    const float* cls_token  = (const float*)d_in[5];
    const float* pos_embed  = (const float*)d_in[6];
    const float* norm_ws    = (const float*)d_in[7];
    const float* in_proj_ws = (const float*)d_in[8];
    const float* conv_ws    = (const float*)d_in[9];
    const float* conv_bs    = (const float*)d_in[10];
    const float* x_proj_ws  = (const float*)d_in[11];
    const float* dt_proj_ws = (const float*)d_in[12];
    const float* dt_proj_bs = (const float*)d_in[13];
    const float* A_logs     = (const float*)d_in[14];
    const float* Ds         = (const float*)d_in[15];
    const float* out_proj_ws= (const float*)d_in[16];
    const float* norm_f_w   = (const float*)d_in[17];
    const float* mlp1_w     = (const float*)d_in[18];
    const float* mlp1_b     = (const float*)d_in[19];
    const float* mlp2_w     = (const float*)d_in[20];
    const float* mlp2_b     = (const float*)d_in[21];
    const float* head_w     = (const float*)d_in[22];
    const float* head_b     = (const float*)d_in[23];

    float* ws = (float*)d_ws;
    size_t off = 0;
    float* v_sem  = ws + off; off += 128 * DM;
    float* h1     = ws + off; off += 128 * 128;
    float* v_stat = ws + off; off += 128 * 128;
    float* cwT    = ws + off; off += 4 * 4 * DI;
    unsigned short* inw_bf = (unsigned short*)(ws + off); off += (size_t)4 * 768 * DM / 2;
    unsigned short* ow_bf  = (unsigned short*)(ws + off); off += (size_t)4 * DM * DI / 2;
    unsigned short* xdtw   = (unsigned short*)(ws + off); off += (size_t)4 * 416 * DI / 2;
    float* chunkbuf = ws + off;
    size_t small_floats = off;

    // per-b floats: rows(401)*[residual 192 + dbl 32 + dtbf 192 + nbf 96 +
    //   xzbf 384 + xcbf 192 + ybf 192] + Hbuf 6*7*2048
    const size_t per_b = (size_t)L_ * (192 + 32 + 192 + 96 + 384 + 192 + 192)
                       + (size_t)6 * 7 * 2048;
    size_t avail = ws_size / sizeof(float);
    avail = (avail > small_floats) ? (avail - small_floats) : 0;
    int Bc = (int)(avail / per_b);
    if (Bc > B_) Bc = B_;
    if (Bc < 1) Bc = 1;

    // weight prep (once per call; ws re-poisoned before every timed call)
    convw_kernel<<<512, 256, 0, stream>>>(in_proj_ws, inw_bf, 4 * 768 * DM);
    convw_kernel<<<512, 256, 0, stream>>>(out_proj_ws, ow_bf, 4 * DM * DI);
    convcw_kernel<<<(4 * 4 * DI + 255) / 256, 256, 0, stream>>>(conv_ws, cwT);
    build_xdtw_kernel<<<(4 * 416 * 384 + 255) / 256, 256, 0, stream>>>(x_proj_ws, dt_proj_ws, xdtw);

    for (int b0 = 0; b0 < B_; b0 += Bc) {
        int bc = (B_ - b0 < Bc) ? (B_ - b0) : Bc;
        int rows = bc * L_;
        float* residual = chunkbuf;
        float* dbl      = residual + (size_t)rows * DM;            // fp32 B,C [rows][32]
        float* Hbuf     = dbl + (size_t)rows * 32;                 // bc*6*7*2048
        unsigned short* dtbf = (unsigned short*)(Hbuf + (size_t)bc * 6 * 7 * 2048);
        unsigned short* nbf  = dtbf + (size_t)rows * DI;           // [rows][192]
        unsigned short* xzbf = nbf + (size_t)rows * DM;            // [rows][768]
        unsigned short* xcbf = xzbf + (size_t)rows * 2 * DI;       // [rows][384]
        unsigned short* ybf  = xcbf + (size_t)rows * DI;           // [rows][384]

        int gmy = (rows + 255) / 256;
        int gmy2 = (rows + 127) / 128;

        embed_kernel<<<rows, DM, 0, stream>>>(imgs + (size_t)b0 * 1600,
                                              pe_w, pe_b, cls_token, pos_embed, residual);
        rms_kernel<<<(rows + 3) / 4, 256, 0, stream>>>(residual, nbf, norm_ws, rows);

        for (int i = 0; i < 4; ++i) {
            // in_proj -> xzbf (bf16): (rows,192)x(768,192)^T
            gemm_bf_t<192><<<dim3(12, gmy), 256, 0, stream>>>(
                nbf, DM, inw_bf + (size_t)i * 768 * DM, DM,
                nullptr, 0, xzbf, 2 * DI, nullptr, 0, 0,
                nullptr, rows, 2 * DI, 0);
            // conv + silu -> xcbf
            int total4 = rows * (DI / 4);
            conv_silu_kernel<<<(total4 + 255) / 256, 256, 0, stream>>>(
                xzbf, cwT + i * 4 * DI, conv_bs + i * DI, xcbf, total4);
            // fused x_proj+dt_proj: cols<384 -> softplus dt bf16, cols>=384 -> B,C fp32
            gemm_bf_t<384><<<dim3(7, gmy), 256, 0, stream>>>(
                xcbf, DI, xdtw + (size_t)i * 416 * DI, DI,
                nullptr, 0, dtbf, DI, dbl, 32, DI,
                dt_proj_bs + i * DI, rows, 416, 1);
            // segmented scan
            scan1_kernel<<<bc * 6 * 7, 64, 0, stream>>>(
                dtbf, xcbf, dbl, A_logs + (size_t)i * DI * DSTATE, Hbuf);
            scan2_kernel<<<bc * 6 * 8, 64, 0, stream>>>(
                dtbf, xcbf, xzbf, dbl, A_logs + (size_t)i * DI * DSTATE,
                Ds + i * DI, Hbuf, ybf);
            // out_proj + residual += y@W^T + fused rms -> nbf (layers 0..2)
            gemm_out_rms<<<dim3(1, gmy2), 256, 0, stream>>>(
                ybf, DI, ow_bf + (size_t)i * DM * DI, DI,
                residual, (i < 3) ? nbf : nullptr,
                norm_ws + (i + 1 < 4 ? i + 1 : 0) * DM, rows);
        }

        final_kernel<<<bc, 64, 0, stream>>>(residual, norm_f_w,
                                            v_sem + (size_t)b0 * DM);
    }

    mlp1_kernel<<<64, 256, 0, stream>>>(pl, iat, mlp1_w, mlp1_b, h1);
    mlp2_kernel<<<64, 256, 0, stream>>>(h1, mlp2_w, mlp2_b, v_stat);
    head_kernel<<<10, 256, 0, stream>>>(v_sem, v_stat, head_w, head_b, (float*)d_out);
}